// Round 3
// baseline (1398.547 us; speedup 1.0000x reference)
//
#include <hip/hip_runtime.h>

// Problem constants: B=4, N=5, levels (64,128,256),(128,64,128),(256,32,64)

struct Bilin { int i00, i01, i10, i11; float w00, w01, w10, w11; };

__device__ __forceinline__ Bilin make_bilin(float ix, float iy, int W, int H) {
    float x0f = floorf(ix), y0f = floorf(iy);
    float wx1 = ix - x0f, wy1 = iy - y0f;
    float wx0 = 1.f - wx1, wy0 = 1.f - wy1;
    int x0 = (int)x0f, y0 = (int)y0f;
    int x1 = x0 + 1, y1 = y0 + 1;
    bool vx0 = (x0 >= 0 && x0 < W), vx1 = (x1 >= 0 && x1 < W);
    bool vy0 = (y0 >= 0 && y0 < H), vy1 = (y1 >= 0 && y1 < H);
    int cx0 = min(max(x0, 0), W - 1), cx1 = min(max(x1, 0), W - 1);
    int cy0 = min(max(y0, 0), H - 1), cy1 = min(max(y1, 0), H - 1);
    Bilin b;
    b.i00 = cy0 * W + cx0; b.i01 = cy0 * W + cx1;
    b.i10 = cy1 * W + cx0; b.i11 = cy1 * W + cx1;
    b.w00 = (vx0 && vy0) ? wx0 * wy0 : 0.f;
    b.w01 = (vx1 && vy0) ? wx1 * wy0 : 0.f;
    b.w10 = (vx0 && vy1) ? wx0 * wy1 : 0.f;
    b.w11 = (vx1 && vy1) ? wx1 * wy1 : 0.f;
    return b;
}

// Inner sample: warped value at integer px (xq,yq) = affine sample of feat
// (align_corners=True on both the base grid and the sampling).
__device__ __forceinline__ Bilin affine_bilin(const float* th, int xq, int yq, int W, int H) {
    float gx = -1.f + 2.f * xq / (float)(W - 1);
    float gy = -1.f + 2.f * yq / (float)(H - 1);
    float tx = th[0] * gx + th[1] * gy + th[2];
    float ty = th[3] * gx + th[4] * gy + th[5];
    float ix = (tx + 1.f) * 0.5f * (W - 1);
    float iy = (ty + 1.f) * 0.5f * (H - 1);
    return make_bilin(ix, iy, W, H);
}

// Affine warp (align_corners=True), level 0 only. Thread = (img, cg16, h, w).
__global__ __launch_bounds__(256) void warp_kernel(
    const float* __restrict__ src, const float* __restrict__ tmat,
    float* __restrict__ dst, int C, int H, int W)
{
    int idx = blockIdx.x * 256 + threadIdx.x;
    int CGn = C >> 4;
    int HW = H * W;
    int total = 20 * CGn * HW;
    if (idx >= total) return;
    int w   = idx % W;
    int h   = (idx / W) % H;
    int cg  = (idx / HW) % CGn;
    int img = idx / (HW * CGn);
    int b = img / 5, n = img % 5;
    const float* th = tmat + (b * 25 + n) * 6;
    float gx = -1.f + 2.f * w / (float)(W - 1);
    float gy = -1.f + 2.f * h / (float)(H - 1);
    float tx = th[0] * gx + th[1] * gy + th[2];
    float ty = th[3] * gx + th[4] * gy + th[5];
    float ix = (tx + 1.f) * 0.5f * (W - 1);
    float iy = (ty + 1.f) * 0.5f * (H - 1);
    Bilin bl = make_bilin(ix, iy, W, H);
    const float* im = src + ((size_t)img * C + cg * 16) * HW;
    float* op = dst + ((size_t)img * C + cg * 16) * HW + h * W + w;
    #pragma unroll 4
    for (int c = 0; c < 16; ++c) {
        const float* pl = im + c * HW;
        op[c * HW] = pl[bl.i00] * bl.w00 + pl[bl.i01] * bl.w01 +
                     pl[bl.i10] * bl.w10 + pl[bl.i11] * bl.w11;
    }
}

// Zero the stats accumulator region (1792 floats).
__global__ void zero_stats(float* s) {
    for (int i = threadIdx.x; i < 1792; i += 256) s[i] = 0.f;
}

// sums -> (mean, rsqrt(var+eps)) in place. n pairs.
__global__ void finalize_stats(float* s, int n, float inv_hw) {
    int i = threadIdx.x;
    if (i < n) {
        float m = s[2 * i] * inv_hw;
        float v = s[2 * i + 1] * inv_hw - m * m;
        s[2 * i]     = m;
        s[2 * i + 1] = rsqrtf(v + 1e-5f);
    }
}

// Pre-transpose conv weights to [cin][pos][COUT].
__global__ void transpose_w(const float* __restrict__ w1, const float* __restrict__ w2,
                            float* __restrict__ wt1, float* __restrict__ wt2) {
    int t = blockIdx.x * 256 + threadIdx.x;
    for (int i = t; i < 128 * 9 * 32; i += 32 * 256) {
        int o = i % 32, pos = (i / 32) % 9, cin = i / 288;
        wt1[i] = w1[o * 1152 + cin * 9 + pos];
    }
    for (int i = t; i < 32 * 9 * 16; i += 32 * 256) {
        int o = i % 16, pos = (i / 16) % 9, cin = i / 144;
        wt2[i] = w2[o * 288 + cin * 9 + pos];
    }
}

__device__ __forceinline__ void load_row10(float* d, const float* rp) {
    float4 a = *reinterpret_cast<const float4*>(rp);
    float4 b = *reinterpret_cast<const float4*>(rp + 4);
    float2 e = *reinterpret_cast<const float2*>(rp + 8);
    d[0] = a.x; d[1] = a.y; d[2] = a.z; d[3] = a.w;
    d[4] = b.x; d[5] = b.y; d[6] = b.z; d[7] = b.w;
    d[8] = e.x; d[9] = e.y;
}

// Direct 3x3 conv v4, pad=1, H=128 W=256.
// Tile 8x64; thread = 8 px x OCP couts. v4 change (the round-2 diagnosis):
// at VGPR=80 the compiler issued the 18 per-channel weight loads JIT per pos
// -> {load, ~100-200cyc wait, 128cyc of FMA} = the measured 56% VALUBusy.
// Fix: stage the ci-chunk weight slice into LDS once per ci (coalesced,
// 2304 floats), then read per-pos weights as wave-uniform LDS *broadcast*
// reads ping-ponged ONE POS AHEAD (ds_read ~120cyc hidden under 64 FMAs =
// 128cyc). Input rows likewise preloaded mid-dy (in[dy+1] at pos 3dy+1).
// SRC: 0 plain NCHW; 1 ego (img p<4 -> plane p*5+0); 2 neigh (p<16 -> b*5+1+j).
// INIT: acc += init (ego partials). NORM: IN+leaky on input. STATS: fused
// per-(img,cout) sum/sumsq via wave-reduce + atomicAdd into statacc.
template<int CIN, int COUT, int SRC, bool INIT, bool NORM, bool STATS>
__global__ __launch_bounds__(256, 2) void conv3x3v4(
    const float* __restrict__ src, const float* __restrict__ wt,
    const float* __restrict__ bias, const float* __restrict__ stats,
    const float* __restrict__ init, float* __restrict__ dst,
    float* __restrict__ statacc)
{
    constexpr int H = 128, W = 256, HW = H * W;
    constexpr int CHUNK = 8, NCH = CIN / CHUNK;
    constexpr int OCP = COUT / 4;
    constexpr int WQN = OCP / 4;          // float4s per pos (2 for conv1, 1 for conv2)
    constexpr int PW = 68;
    constexpr int WSLICE = CHUNK * 9 * COUT;
    __shared__ __align__(16) float s_in[CHUNK][10][PW];
    __shared__ __align__(16) float s_w[WSLICE];

    int tid = threadIdx.x, bi = blockIdx.x;
    int p = bi >> 6, rem = bi & 63;
    int h_base = (rem >> 2) * 8;
    int w_base = (rem & 3) * 64;
    int cg = tid >> 6, sg = tid & 63;
    int r = sg & 7, cw = (sg >> 3) * 8;
    int cg_u = __builtin_amdgcn_readfirstlane(cg);

    const float* base;
    if (SRC == 1)      base = src + (size_t)(p * 5) * 64 * HW;
    else if (SRC == 2) { int bb = p >> 2, jm = p & 3; base = src + (size_t)((bb * 5 + 1 + jm) * 64) * HW; }
    else               base = src + (size_t)p * CIN * HW;

    // staging positions: e = tid + k*256 over the 10x66 halo tile (660 slots)
    int gofs[3], lofs[3];
    unsigned pvm = 0, ivm = 0;
    #pragma unroll
    for (int k = 0; k < 3; ++k) {
        int e = tid + k * 256;
        bool pv = (e < 660);
        int row = e / 66, col = e % 66;
        int gy = h_base + row - 1, gx = w_base + col - 1;
        bool iv = pv && gy >= 0 && gy < H && gx >= 0 && gx < W;
        gofs[k] = iv ? (gy * W + gx) : 0;
        lofs[k] = pv ? (row * PW + col) : 0;
        pvm |= (pv ? 1u : 0u) << k;
        ivm |= (iv ? 1u : 0u) << k;
    }
    float* lds = &s_in[0][0][0];

    float acc[OCP][8];
    #pragma unroll
    for (int o = 0; o < OCP; ++o)
        #pragma unroll
        for (int i = 0; i < 8; ++i) acc[o][i] = 0.f;

    float pf[3][CHUNK];
    // prefetch chunk 0
    #pragma unroll
    for (int k = 0; k < 3; ++k)
        if (pvm >> k & 1)
            #pragma unroll
            for (int c = 0; c < CHUNK; ++c)
                pf[k][c] = base[(size_t)c * HW + gofs[k]];

    for (int ci = 0; ci < NCH; ++ci) {
        if (ci) __syncthreads();
        // store prefetched chunk to LDS (apply IN+leaky here if NORM)
        float mrs[NORM ? 2 * CHUNK : 1];
        if (NORM) {
            const float4* sp = (const float4*)(stats + (size_t)(p * CIN + ci * CHUNK) * 2);
            #pragma unroll
            for (int q = 0; q < CHUNK / 2; ++q) {
                float4 v = sp[q];
                mrs[q * 4] = v.x; mrs[q * 4 + 1] = v.y; mrs[q * 4 + 2] = v.z; mrs[q * 4 + 3] = v.w;
            }
        }
        #pragma unroll
        for (int k = 0; k < 3; ++k) {
            if (pvm >> k & 1) {
                #pragma unroll
                for (int c = 0; c < CHUNK; ++c) {
                    float v = (ivm >> k & 1) ? pf[k][c] : 0.f;
                    if (NORM && (ivm >> k & 1)) {
                        v = (v - mrs[2 * c]) * mrs[2 * c + 1];
                        v = v >= 0.f ? v : 0.01f * v;
                    }
                    lds[c * (10 * PW) + lofs[k]] = v;
                }
            }
        }
        // stage this ci's weight slice into LDS (contiguous in WT layout)
        {
            const float* wsl = wt + (size_t)ci * WSLICE;
            for (int t = tid; t < WSLICE; t += 256) s_w[t] = wsl[t];
        }
        __syncthreads();
        // prefetch next input chunk
        if (ci + 1 < NCH) {
            const float* nb = base + (size_t)(ci + 1) * CHUNK * HW;
            #pragma unroll
            for (int k = 0; k < 3; ++k)
                if (pvm >> k & 1)
                    #pragma unroll
                    for (int c = 0; c < CHUNK; ++c)
                        pf[k][c] = nb[(size_t)c * HW + gofs[k]];
        }
        // compute chunk ci
        #pragma unroll 1
        for (int c = 0; c < CHUNK; ++c) {
            const float* swp = s_w + (size_t)(c * 9) * COUT + cg_u * OCP;
            float4 wq[2][WQN];            // ping-pong; static indices after unroll
            #pragma unroll
            for (int q = 0; q < WQN; ++q)
                wq[0][q] = *reinterpret_cast<const float4*>(swp + q * 4);
            float in[3][10];
            load_row10(&in[0][0], &s_in[c][r][cw]);
            #pragma unroll
            for (int pos = 0; pos < 9; ++pos) {
                const int dy = pos / 3, dx = pos % 3;
                // issue next pos's weight broadcast reads (hidden under FMAs)
                if (pos < 8) {
                    const float* np = swp + (pos + 1) * COUT;
                    #pragma unroll
                    for (int q = 0; q < WQN; ++q)
                        wq[(pos + 1) & 1][q] = *reinterpret_cast<const float4*>(np + q * 4);
                }
                // preload next dy's input row mid-way through this dy
                if (pos == 1) load_row10(&in[1][0], &s_in[c][r + 1][cw]);
                if (pos == 4) load_row10(&in[2][0], &s_in[c][r + 2][cw]);
                float wv[OCP];
                #pragma unroll
                for (int q = 0; q < WQN; ++q) {
                    wv[q * 4]     = wq[pos & 1][q].x;
                    wv[q * 4 + 1] = wq[pos & 1][q].y;
                    wv[q * 4 + 2] = wq[pos & 1][q].z;
                    wv[q * 4 + 3] = wq[pos & 1][q].w;
                }
                #pragma unroll
                for (int o = 0; o < OCP; ++o)
                    #pragma unroll
                    for (int px = 0; px < 8; ++px)
                        acc[o][px] = fmaf(in[dy][dx + px], wv[o], acc[o][px]);
            }
        }
    }
    // epilogue
    int hh = h_base + r, ww = w_base + cw;
    #pragma unroll
    for (int o = 0; o < OCP; ++o) {
        int oc = cg * OCP + o;
        float bv = (SRC == 1) ? 0.f : bias[oc];
        float add[8];
        #pragma unroll
        for (int i = 0; i < 8; ++i) add[i] = bv;
        if (INIT) {
            int bb = (SRC == 2) ? (p >> 2) : p;
            const float* ip = init + ((size_t)bb * COUT + oc) * HW + hh * W + ww;
            float4 e0 = *reinterpret_cast<const float4*>(ip);
            float4 e1 = *reinterpret_cast<const float4*>(ip + 4);
            add[0] += e0.x; add[1] += e0.y; add[2] += e0.z; add[3] += e0.w;
            add[4] += e1.x; add[5] += e1.y; add[6] += e1.z; add[7] += e1.w;
        }
        float vals[8];
        #pragma unroll
        for (int i = 0; i < 8; ++i) vals[i] = acc[o][i] + add[i];
        float* op = dst + (((size_t)p * COUT + oc) * H + hh) * W + ww;
        *reinterpret_cast<float4*>(op)     = make_float4(vals[0], vals[1], vals[2], vals[3]);
        *reinterpret_cast<float4*>(op + 4) = make_float4(vals[4], vals[5], vals[6], vals[7]);
        if (STATS) {
            float s = 0.f, s2 = 0.f;
            #pragma unroll
            for (int i = 0; i < 8; ++i) { s += vals[i]; s2 += vals[i] * vals[i]; }
            #pragma unroll
            for (int off = 32; off > 0; off >>= 1) {
                s  += __shfl_down(s, off);
                s2 += __shfl_down(s2, off);
            }
            if (sg == 0) {
                atomicAdd(&statacc[(size_t)(p * COUT + oc) * 2],     s);
                atomicAdd(&statacc[(size_t)(p * COUT + oc) * 2 + 1], s2);
            }
        }
    }
}

// 1x1 conv with fused IN+leaky on input; optional fused stats on output.
template<int CIN, int COUT, bool STATS>
__global__ __launch_bounds__(256) void conv1x1_kernel(
    const float* __restrict__ src, const float* __restrict__ wgt,
    const float* __restrict__ bias, const float* __restrict__ stats,
    float* __restrict__ dst, float* __restrict__ statacc)
{
    constexpr int HW = 128 * 256;
    __shared__ float s_w[COUT * CIN];
    __shared__ float s_b[COUT];
    __shared__ float s_part[4][2 * COUT];
    int tid = threadIdx.x;
    for (int t = tid; t < COUT * CIN; t += 256) s_w[t] = wgt[t];
    if (tid < COUT) s_b[tid] = bias[tid];
    __syncthreads();
    int p  = blockIdx.x >> 7;
    int px = ((blockIdx.x & 127) << 8) + tid;
    float in[CIN];
    #pragma unroll
    for (int c = 0; c < CIN; ++c) {
        float v  = src[((size_t)p * CIN + c) * HW + px];
        float m  = stats[(p * CIN + c) * 2];
        float rs = stats[(p * CIN + c) * 2 + 1];
        v = (v - m) * rs;
        in[c] = v >= 0.f ? v : 0.01f * v;
    }
    float val[COUT];
    #pragma unroll
    for (int o = 0; o < COUT; ++o) {
        float s = s_b[o];
        #pragma unroll
        for (int c = 0; c < CIN; ++c) s = fmaf(in[c], s_w[o * CIN + c], s);
        val[o] = s;
        dst[((size_t)p * COUT + o) * HW + px] = s;
    }
    if (STATS) {
        int wv = tid >> 6, ln = tid & 63;
        #pragma unroll
        for (int o = 0; o < COUT; ++o) {
            float s = val[o], s2 = val[o] * val[o];
            #pragma unroll
            for (int off = 32; off > 0; off >>= 1) {
                s  += __shfl_down(s, off);
                s2 += __shfl_down(s2, off);
            }
            if (ln == 0) { s_part[wv][o * 2] = s; s_part[wv][o * 2 + 1] = s2; }
        }
        __syncthreads();
        if (tid < 2 * COUT) {
            float t = s_part[0][tid] + s_part[1][tid] + s_part[2][tid] + s_part[3][tid];
            atomicAdd(&statacc[(size_t)p * COUT * 2 + tid], t);
        }
    }
}

// Level-0 fusion: deform-sample 4 neighbors from W0 + max with ego plane.
// Thread = (b, cg16, h, w), 16 channels; 2048 blocks (100% grid cap), no
// min-waves clause (forcing 8/EU capped VGPR at 32 -> spills, round 1).
// XCD-chunked bijective swizzle (2048%8==0) for row reuse in per-XCD L2.
__global__ __launch_bounds__(256) void fuse0_kernel(
    const float* __restrict__ W0, const float* __restrict__ grid,
    float* __restrict__ out)
{
    constexpr int HW = 32768;
    constexpr int CPT = 16;
    int bid = blockIdx.x;
    int swz = (bid & 7) * 256 + (bid >> 3);
    int idx = swz * 256 + threadIdx.x;   // 4 * 4 * 32768
    int px = idx & 32767;
    int cg = (idx >> 15) & 3;
    int b  = idx >> 17;
    int w = px & 255, h = px >> 8;
    float bx = (w + 0.5f) * (2.f / 256.f) - 1.f;
    float by = (h + 0.5f) * (2.f / 128.f) - 1.f;
    Bilin bl[4];
    #pragma unroll
    for (int j = 0; j < 4; ++j) {
        const float2 g = *reinterpret_cast<const float2*>(
            grid + ((size_t)(b * 4 + j)) * 65536 + (size_t)px * 2);
        float ix = ((g.x + bx + 1.f) * 256.f - 1.f) * 0.5f;
        float iy = ((g.y + by + 1.f) * 128.f - 1.f) * 0.5f;
        bl[j] = make_bilin(ix, iy, 256, 128);
    }
    const float* ego = W0 + ((size_t)(b * 5) * 64 + cg * CPT) * HW + px;
    float* op = out + ((size_t)b * 64 + cg * CPT) * HW + px;
    #pragma unroll 2
    for (int c = 0; c < CPT; ++c) {
        float mx = ego[(size_t)c * HW];
        #pragma unroll
        for (int j = 0; j < 4; ++j) {
            const float* pl = W0 + ((size_t)(b * 5 + 1 + j) * 64 + cg * CPT + c) * HW;
            float s = pl[bl[j].i00] * bl[j].w00 + pl[bl[j].i01] * bl[j].w01 +
                      pl[bl[j].i10] * bl[j].w10 + pl[bl[j].i11] * bl[j].w11;
            mx = fmaxf(mx, s);
        }
        op[(size_t)c * HW] = mx;
    }
}

// Levels 1,2 fusion, composed: no materialized warp. Ego = inline affine
// sample; neighbor = outer bilinear (align_corners=False) over warped px,
// each warped px = inner affine bilinear of feat — 16 reads with
// premultiplied weights. Exact modulo fp association.
// CPT halved -> 1024 blocks (grid occupancy cap 25%->50%; VALUBusy was low,
// latency-bound like fuse0); XCD-chunked bijective swizzle (1024%8==0).
template<int C, int CPT, int SH, int HS, int WS>
__global__ __launch_bounds__(256) void fuse_comp(
    const float* __restrict__ feat, const float* __restrict__ tmat,
    const float* __restrict__ grid, float* __restrict__ out)
{
    constexpr int HW = HS * WS;
    constexpr int NCG = C / CPT;
    constexpr int NBLK = 4 * NCG * HW / 256;   // 1024 for both levels
    int bid = blockIdx.x;
    int swz = (bid & 7) * (NBLK / 8) + (bid >> 3);
    int idx = swz * 256 + threadIdx.x;
    if (idx >= 4 * NCG * HW) return;
    int px = idx % HW;
    int cg = (idx / HW) % NCG;
    int b  = idx / (HW * NCG);
    int w = px % WS, h = px / WS;

    float m[CPT];
    {   // ego
        const float* th = tmat + (size_t)(b * 25) * 6;
        float t0 = th[0], t1 = th[1], t2 = th[2], t3 = th[3], t4 = th[4], t5 = th[5];
        float thr[6] = {t0, t1, t2, t3, t4, t5};
        Bilin bi = affine_bilin(thr, w, h, WS, HS);
        const float* pb = feat + ((size_t)(b * 5) * C + cg * CPT) * HW;
        #pragma unroll 4
        for (int c = 0; c < CPT; ++c) {
            const float* pl = pb + (size_t)c * HW;
            m[c] = pl[bi.i00] * bi.w00 + pl[bi.i01] * bi.w01 +
                   pl[bi.i10] * bi.w10 + pl[bi.i11] * bi.w11;
        }
    }
    int h0 = h << SH, w0 = w << SH;
    float bx = (w0 + 0.5f) * (2.f / 256.f) - 1.f;
    float by = (h0 + 0.5f) * (2.f / 128.f) - 1.f;
    for (int j = 0; j < 4; ++j) {
        const float2 g = *reinterpret_cast<const float2*>(
            grid + ((size_t)(b * 4 + j)) * 65536 + (size_t)(h0 * 256 + w0) * 2);
        float ix = ((g.x + bx + 1.f) * WS - 1.f) * 0.5f;
        float iy = ((g.y + by + 1.f) * HS - 1.f) * 0.5f;
        // outer corners
        float x0f = floorf(ix), y0f = floorf(iy);
        float wx1 = ix - x0f, wy1 = iy - y0f;
        float wx0 = 1.f - wx1, wy0 = 1.f - wy1;
        int x0 = (int)x0f, y0 = (int)y0f, x1 = x0 + 1, y1 = y0 + 1;
        bool vx0 = (x0 >= 0 && x0 < WS), vx1 = (x1 >= 0 && x1 < WS);
        bool vy0 = (y0 >= 0 && y0 < HS), vy1 = (y1 >= 0 && y1 < HS);
        int cx0 = min(max(x0, 0), WS - 1), cx1 = min(max(x1, 0), WS - 1);
        int cy0 = min(max(y0, 0), HS - 1), cy1 = min(max(y1, 0), HS - 1);
        float ow[4] = { (vx0 && vy0) ? wx0 * wy0 : 0.f,
                        (vx1 && vy0) ? wx1 * wy0 : 0.f,
                        (vx0 && vy1) ? wx0 * wy1 : 0.f,
                        (vx1 && vy1) ? wx1 * wy1 : 0.f };
        int qx[4] = { cx0, cx1, cx0, cx1 };
        int qy[4] = { cy0, cy0, cy1, cy1 };
        const float* th = tmat + (size_t)(b * 25 + 1 + j) * 6;
        float thr[6] = { th[0], th[1], th[2], th[3], th[4], th[5] };
        Bilin in_[4];
        #pragma unroll
        for (int q = 0; q < 4; ++q) {
            in_[q] = affine_bilin(thr, qx[q], qy[q], WS, HS);
            in_[q].w00 *= ow[q]; in_[q].w01 *= ow[q];
            in_[q].w10 *= ow[q]; in_[q].w11 *= ow[q];
        }
        const float* pb = feat + ((size_t)(b * 5 + 1 + j) * C + cg * CPT) * HW;
        #pragma unroll 2
        for (int c = 0; c < CPT; ++c) {
            const float* pl = pb + (size_t)c * HW;
            float s = 0.f;
            #pragma unroll
            for (int q = 0; q < 4; ++q)
                s += pl[in_[q].i00] * in_[q].w00 + pl[in_[q].i01] * in_[q].w01 +
                     pl[in_[q].i10] * in_[q].w10 + pl[in_[q].i11] * in_[q].w11;
            m[c] = fmaxf(m[c], s);
        }
    }
    float* op = out + ((size_t)b * C + cg * CPT) * HW + px;
    #pragma unroll
    for (int c = 0; c < CPT; ++c) op[(size_t)c * HW] = m[c];
}

extern "C" void kernel_launch(void* const* d_in, const int* in_sizes, int n_in,
                              void* d_out, int out_size, void* d_ws, size_t ws_size,
                              hipStream_t stream)
{
    const float* feat0 = (const float*)d_in[0];
    const float* feat1 = (const float*)d_in[1];
    const float* feat2 = (const float*)d_in[2];
    const float* tmat  = (const float*)d_in[3];
    const float* w1 = (const float*)d_in[5];
    const float* b1 = (const float*)d_in[6];
    const float* w2 = (const float*)d_in[7];
    const float* b2 = (const float*)d_in[8];
    const float* w3 = (const float*)d_in[9];
    const float* b3 = (const float*)d_in[10];
    const float* w4 = (const float*)d_in[11];
    const float* b4 = (const float*)d_in[12];
    float* out = (float*)d_out;
    float* ws  = (float*)d_ws;

    // workspace layout (floats)
    const size_t nW0 = 41943040;  // 20*64*128*256
    const size_t nX1 = 16777216;  // 16*32*128*256
    const size_t nX2 = 8388608;   // 16*16*128*256
    const size_t nX3 = 4194304;   // 16*8*128*256
    const size_t nG  = 2097152;   // 16*2*128*256
    const size_t nS  = 2048;
    const size_t nWT = 36864 + 4608;
    const size_t needed = (nW0 + nX1 + nX2 + nX3 + nG + nS + nWT) * 4;
    if (ws_size < needed) return;

    float* W0  = ws;
    float* X1  = W0 + nW0;
    float* X2  = X1 + nX1;
    float* X3  = X2 + nX2;
    float* G   = X3 + nX3;
    float* S   = G  + nG;    // stats sums: X1@0(1024), X2@1024(512), X3@1536(256)
    float* WT1 = S  + nS;
    float* WT2 = WT1 + 36864;
    float* E   = X2;         // ego partials (4*32*32768) overlay X2 (dead until conv2)

    zero_stats<<<1, 256, 0, stream>>>(S);
    transpose_w<<<32, 256, 0, stream>>>(w1, w2, WT1, WT2);

    // level-0 affine warp (needed by conv1 and fuse0)
    warp_kernel<<<10240, 256, 0, stream>>>(feat0, tmat, W0, 64, 128, 256);

    // offset CNN: conv1 split into ego (once per batch) + neighbor (+init)
    conv3x3v4<64, 32, 1, false, false, false><<<256,  256, 0, stream>>>(W0, WT1, b1, nullptr, nullptr, E, nullptr);
    conv3x3v4<64, 32, 2, true,  false, true ><<<1024, 256, 0, stream>>>(W0, WT1 + 8 * 8 * 9 * 32, b1, nullptr, E, X1, S);
    finalize_stats<<<1, 512, 0, stream>>>(S, 512, 1.f / 32768.f);
    conv3x3v4<32, 16, 0, false, true,  true ><<<1024, 256, 0, stream>>>(X1, WT2, b2, S, nullptr, X2, S + 1024);
    finalize_stats<<<1, 256, 0, stream>>>(S + 1024, 256, 1.f / 32768.f);
    conv1x1_kernel<16, 8, true ><<<2048, 256, 0, stream>>>(X2, w3, b3, S + 1024, X3, S + 1536);
    finalize_stats<<<1, 128, 0, stream>>>(S + 1536, 128, 1.f / 32768.f);
    conv1x1_kernel<8, 2, false><<<2048, 256, 0, stream>>>(X3, w4, b4, S + 1536, G, nullptr);

    // fusion
    fuse0_kernel<<<2048, 256, 0, stream>>>(W0, G, out);
    fuse_comp<128, 16, 1, 64, 128><<<1024, 256, 0, stream>>>(feat1, tmat, G, out + 8388608);
    fuse_comp<256, 8, 2, 32,  64><<<1024, 256, 0, stream>>>(feat2, tmat, G, out + 12582912);
}

// Round 4
// 1333.754 us; speedup vs baseline: 1.0486x; 1.0486x over previous
//
#include <hip/hip_runtime.h>

// Problem constants: B=4, N=5, levels (64,128,256),(128,64,128),(256,32,64)

struct Bilin { int i00, i01, i10, i11; float w00, w01, w10, w11; };

__device__ __forceinline__ Bilin make_bilin(float ix, float iy, int W, int H) {
    float x0f = floorf(ix), y0f = floorf(iy);
    float wx1 = ix - x0f, wy1 = iy - y0f;
    float wx0 = 1.f - wx1, wy0 = 1.f - wy1;
    int x0 = (int)x0f, y0 = (int)y0f;
    int x1 = x0 + 1, y1 = y0 + 1;
    bool vx0 = (x0 >= 0 && x0 < W), vx1 = (x1 >= 0 && x1 < W);
    bool vy0 = (y0 >= 0 && y0 < H), vy1 = (y1 >= 0 && y1 < H);
    int cx0 = min(max(x0, 0), W - 1), cx1 = min(max(x1, 0), W - 1);
    int cy0 = min(max(y0, 0), H - 1), cy1 = min(max(y1, 0), H - 1);
    Bilin b;
    b.i00 = cy0 * W + cx0; b.i01 = cy0 * W + cx1;
    b.i10 = cy1 * W + cx0; b.i11 = cy1 * W + cx1;
    b.w00 = (vx0 && vy0) ? wx0 * wy0 : 0.f;
    b.w01 = (vx1 && vy0) ? wx1 * wy0 : 0.f;
    b.w10 = (vx0 && vy1) ? wx0 * wy1 : 0.f;
    b.w11 = (vx1 && vy1) ? wx1 * wy1 : 0.f;
    return b;
}

// Inner sample: warped value at integer px (xq,yq) = affine sample of feat
// (align_corners=True on both the base grid and the sampling).
__device__ __forceinline__ Bilin affine_bilin(const float* th, int xq, int yq, int W, int H) {
    float gx = -1.f + 2.f * xq / (float)(W - 1);
    float gy = -1.f + 2.f * yq / (float)(H - 1);
    float tx = th[0] * gx + th[1] * gy + th[2];
    float ty = th[3] * gx + th[4] * gy + th[5];
    float ix = (tx + 1.f) * 0.5f * (W - 1);
    float iy = (ty + 1.f) * 0.5f * (H - 1);
    return make_bilin(ix, iy, W, H);
}

// Affine warp (align_corners=True), level 0 only. Thread = (img, cg16, h, w).
__global__ __launch_bounds__(256) void warp_kernel(
    const float* __restrict__ src, const float* __restrict__ tmat,
    float* __restrict__ dst, int C, int H, int W)
{
    int idx = blockIdx.x * 256 + threadIdx.x;
    int CGn = C >> 4;
    int HW = H * W;
    int total = 20 * CGn * HW;
    if (idx >= total) return;
    int w   = idx % W;
    int h   = (idx / W) % H;
    int cg  = (idx / HW) % CGn;
    int img = idx / (HW * CGn);
    int b = img / 5, n = img % 5;
    const float* th = tmat + (b * 25 + n) * 6;
    float gx = -1.f + 2.f * w / (float)(W - 1);
    float gy = -1.f + 2.f * h / (float)(H - 1);
    float tx = th[0] * gx + th[1] * gy + th[2];
    float ty = th[3] * gx + th[4] * gy + th[5];
    float ix = (tx + 1.f) * 0.5f * (W - 1);
    float iy = (ty + 1.f) * 0.5f * (H - 1);
    Bilin bl = make_bilin(ix, iy, W, H);
    const float* im = src + ((size_t)img * C + cg * 16) * HW;
    float* op = dst + ((size_t)img * C + cg * 16) * HW + h * W + w;
    #pragma unroll 4
    for (int c = 0; c < 16; ++c) {
        const float* pl = im + c * HW;
        op[c * HW] = pl[bl.i00] * bl.w00 + pl[bl.i01] * bl.w01 +
                     pl[bl.i10] * bl.w10 + pl[bl.i11] * bl.w11;
    }
}

// Zero the stats accumulator region (1792 floats).
__global__ void zero_stats(float* s) {
    for (int i = threadIdx.x; i < 1792; i += 256) s[i] = 0.f;
}

// sums -> (mean, rsqrt(var+eps)) in place. n pairs.
__global__ void finalize_stats(float* s, int n, float inv_hw) {
    int i = threadIdx.x;
    if (i < n) {
        float m = s[2 * i] * inv_hw;
        float v = s[2 * i + 1] * inv_hw - m * m;
        s[2 * i]     = m;
        s[2 * i + 1] = rsqrtf(v + 1e-5f);
    }
}

// Pre-transpose conv weights to [cin][pos][COUT].
__global__ void transpose_w(const float* __restrict__ w1, const float* __restrict__ w2,
                            float* __restrict__ wt1, float* __restrict__ wt2) {
    int t = blockIdx.x * 256 + threadIdx.x;
    for (int i = t; i < 128 * 9 * 32; i += 32 * 256) {
        int o = i % 32, pos = (i / 32) % 9, cin = i / 288;
        wt1[i] = w1[o * 1152 + cin * 9 + pos];
    }
    for (int i = t; i < 32 * 9 * 16; i += 32 * 256) {
        int o = i % 16, pos = (i / 16) % 9, cin = i / 144;
        wt2[i] = w2[o * 288 + cin * 9 + pos];
    }
}

// Direct 3x3 conv v3 (reverted: v4's LDS-weight pipeline regressed 272->317;
// with ~2 blocks/CU there is no TLP to hide the extra ds_read latency and the
// per-ci weight staging loop sat on the critical path. v3 = known 272 µs).
// Tile 8x64; thread = 8 px x OCP couts. Weights via wave-uniform global loads
// (pre-transposed [cin][pos][COUT]); input staged through LDS with a
// register-prefetch pipeline (load chunk ci+1 while computing ci).
// SRC: 0 plain NCHW; 1 ego (img p<4 -> plane p*5+0); 2 neigh (p<16 -> b*5+1+j).
// INIT: acc += init (ego partials). NORM: IN+leaky on input. STATS: fused
// per-(img,cout) sum/sumsq via wave-reduce + atomicAdd into statacc.
template<int CIN, int COUT, int SRC, bool INIT, bool NORM, bool STATS>
__global__ __launch_bounds__(256, 2) void conv3x3v3(
    const float* __restrict__ src, const float* __restrict__ wt,
    const float* __restrict__ bias, const float* __restrict__ stats,
    const float* __restrict__ init, float* __restrict__ dst,
    float* __restrict__ statacc)
{
    constexpr int H = 128, W = 256, HW = H * W;
    constexpr int CHUNK = 8, NCH = CIN / CHUNK;
    constexpr int OCP = COUT / 4;
    constexpr int PW = 68;
    __shared__ __align__(16) float s_in[CHUNK][10][PW];

    int tid = threadIdx.x, bi = blockIdx.x;
    int p = bi >> 6, rem = bi & 63;
    int h_base = (rem >> 2) * 8;
    int w_base = (rem & 3) * 64;
    int cg = tid >> 6, sg = tid & 63;
    int r = sg & 7, cw = (sg >> 3) * 8;
    int cg_u = __builtin_amdgcn_readfirstlane(cg);

    const float* base;
    if (SRC == 1)      base = src + (size_t)(p * 5) * 64 * HW;
    else if (SRC == 2) { int bb = p >> 2, jm = p & 3; base = src + (size_t)((bb * 5 + 1 + jm) * 64) * HW; }
    else               base = src + (size_t)p * CIN * HW;

    // staging positions: e = tid + k*256 over the 10x66 halo tile (660 slots)
    int gofs[3], lofs[3];
    unsigned pvm = 0, ivm = 0;
    #pragma unroll
    for (int k = 0; k < 3; ++k) {
        int e = tid + k * 256;
        bool pv = (e < 660);
        int row = e / 66, col = e % 66;
        int gy = h_base + row - 1, gx = w_base + col - 1;
        bool iv = pv && gy >= 0 && gy < H && gx >= 0 && gx < W;
        gofs[k] = iv ? (gy * W + gx) : 0;
        lofs[k] = pv ? (row * PW + col) : 0;
        pvm |= (pv ? 1u : 0u) << k;
        ivm |= (iv ? 1u : 0u) << k;
    }
    float* lds = &s_in[0][0][0];

    float acc[OCP][8];
    #pragma unroll
    for (int o = 0; o < OCP; ++o)
        #pragma unroll
        for (int i = 0; i < 8; ++i) acc[o][i] = 0.f;

    float pf[3][CHUNK];
    // prefetch chunk 0
    #pragma unroll
    for (int k = 0; k < 3; ++k)
        if (pvm >> k & 1)
            #pragma unroll
            for (int c = 0; c < CHUNK; ++c)
                pf[k][c] = base[(size_t)c * HW + gofs[k]];

    for (int ci = 0; ci < NCH; ++ci) {
        if (ci) __syncthreads();
        // store prefetched chunk to LDS (apply IN+leaky here if NORM)
        float mrs[NORM ? 2 * CHUNK : 1];
        if (NORM) {
            const float4* sp = (const float4*)(stats + (size_t)(p * CIN + ci * CHUNK) * 2);
            #pragma unroll
            for (int q = 0; q < CHUNK / 2; ++q) {
                float4 v = sp[q];
                mrs[q * 4] = v.x; mrs[q * 4 + 1] = v.y; mrs[q * 4 + 2] = v.z; mrs[q * 4 + 3] = v.w;
            }
        }
        #pragma unroll
        for (int k = 0; k < 3; ++k) {
            if (pvm >> k & 1) {
                #pragma unroll
                for (int c = 0; c < CHUNK; ++c) {
                    float v = (ivm >> k & 1) ? pf[k][c] : 0.f;
                    if (NORM && (ivm >> k & 1)) {
                        v = (v - mrs[2 * c]) * mrs[2 * c + 1];
                        v = v >= 0.f ? v : 0.01f * v;
                    }
                    lds[c * (10 * PW) + lofs[k]] = v;
                }
            }
        }
        __syncthreads();
        // prefetch next chunk
        if (ci + 1 < NCH) {
            const float* nb = base + (size_t)(ci + 1) * CHUNK * HW;
            #pragma unroll
            for (int k = 0; k < 3; ++k)
                if (pvm >> k & 1)
                    #pragma unroll
                    for (int c = 0; c < CHUNK; ++c)
                        pf[k][c] = nb[(size_t)c * HW + gofs[k]];
        }
        // compute chunk ci
        #pragma unroll 1
        for (int c = 0; c < CHUNK; ++c) {
            float in[3][10];
            #pragma unroll
            for (int dy = 0; dy < 3; ++dy) {
                const float* rp = &s_in[c][r + dy][cw];
                float4 a = *reinterpret_cast<const float4*>(rp);
                float4 b = *reinterpret_cast<const float4*>(rp + 4);
                float2 e = *reinterpret_cast<const float2*>(rp + 8);
                in[dy][0] = a.x; in[dy][1] = a.y; in[dy][2] = a.z; in[dy][3] = a.w;
                in[dy][4] = b.x; in[dy][5] = b.y; in[dy][6] = b.z; in[dy][7] = b.w;
                in[dy][8] = e.x; in[dy][9] = e.y;
            }
            const float* wp = wt + (size_t)((ci * CHUNK + c) * 9) * COUT + cg_u * OCP;
            #pragma unroll
            for (int pos = 0; pos < 9; ++pos) {
                const int dy = pos / 3, dx = pos % 3;
                float wv[OCP];
                #pragma unroll
                for (int oq = 0; oq < OCP; oq += 4) {
                    float4 wq = *reinterpret_cast<const float4*>(wp + pos * COUT + oq);
                    wv[oq] = wq.x; wv[oq + 1] = wq.y; wv[oq + 2] = wq.z; wv[oq + 3] = wq.w;
                }
                #pragma unroll
                for (int o = 0; o < OCP; ++o)
                    #pragma unroll
                    for (int px = 0; px < 8; ++px)
                        acc[o][px] = fmaf(in[dy][dx + px], wv[o], acc[o][px]);
            }
        }
    }
    // epilogue
    int hh = h_base + r, ww = w_base + cw;
    #pragma unroll
    for (int o = 0; o < OCP; ++o) {
        int oc = cg * OCP + o;
        float bv = (SRC == 1) ? 0.f : bias[oc];
        float add[8];
        #pragma unroll
        for (int i = 0; i < 8; ++i) add[i] = bv;
        if (INIT) {
            int bb = (SRC == 2) ? (p >> 2) : p;
            const float* ip = init + ((size_t)bb * COUT + oc) * HW + hh * W + ww;
            float4 e0 = *reinterpret_cast<const float4*>(ip);
            float4 e1 = *reinterpret_cast<const float4*>(ip + 4);
            add[0] += e0.x; add[1] += e0.y; add[2] += e0.z; add[3] += e0.w;
            add[4] += e1.x; add[5] += e1.y; add[6] += e1.z; add[7] += e1.w;
        }
        float vals[8];
        #pragma unroll
        for (int i = 0; i < 8; ++i) vals[i] = acc[o][i] + add[i];
        float* op = dst + (((size_t)p * COUT + oc) * H + hh) * W + ww;
        *reinterpret_cast<float4*>(op)     = make_float4(vals[0], vals[1], vals[2], vals[3]);
        *reinterpret_cast<float4*>(op + 4) = make_float4(vals[4], vals[5], vals[6], vals[7]);
        if (STATS) {
            float s = 0.f, s2 = 0.f;
            #pragma unroll
            for (int i = 0; i < 8; ++i) { s += vals[i]; s2 += vals[i] * vals[i]; }
            #pragma unroll
            for (int off = 32; off > 0; off >>= 1) {
                s  += __shfl_down(s, off);
                s2 += __shfl_down(s2, off);
            }
            if (sg == 0) {
                atomicAdd(&statacc[(size_t)(p * COUT + oc) * 2],     s);
                atomicAdd(&statacc[(size_t)(p * COUT + oc) * 2 + 1], s2);
            }
        }
    }
}

// 1x1 conv with fused IN+leaky on input; optional fused stats on output.
template<int CIN, int COUT, bool STATS>
__global__ __launch_bounds__(256) void conv1x1_kernel(
    const float* __restrict__ src, const float* __restrict__ wgt,
    const float* __restrict__ bias, const float* __restrict__ stats,
    float* __restrict__ dst, float* __restrict__ statacc)
{
    constexpr int HW = 128 * 256;
    __shared__ float s_w[COUT * CIN];
    __shared__ float s_b[COUT];
    __shared__ float s_part[4][2 * COUT];
    int tid = threadIdx.x;
    for (int t = tid; t < COUT * CIN; t += 256) s_w[t] = wgt[t];
    if (tid < COUT) s_b[tid] = bias[tid];
    __syncthreads();
    int p  = blockIdx.x >> 7;
    int px = ((blockIdx.x & 127) << 8) + tid;
    float in[CIN];
    #pragma unroll
    for (int c = 0; c < CIN; ++c) {
        float v  = src[((size_t)p * CIN + c) * HW + px];
        float m  = stats[(p * CIN + c) * 2];
        float rs = stats[(p * CIN + c) * 2 + 1];
        v = (v - m) * rs;
        in[c] = v >= 0.f ? v : 0.01f * v;
    }
    float val[COUT];
    #pragma unroll
    for (int o = 0; o < COUT; ++o) {
        float s = s_b[o];
        #pragma unroll
        for (int c = 0; c < CIN; ++c) s = fmaf(in[c], s_w[o * CIN + c], s);
        val[o] = s;
        dst[((size_t)p * COUT + o) * HW + px] = s;
    }
    if (STATS) {
        int wv = tid >> 6, ln = tid & 63;
        #pragma unroll
        for (int o = 0; o < COUT; ++o) {
            float s = val[o], s2 = val[o] * val[o];
            #pragma unroll
            for (int off = 32; off > 0; off >>= 1) {
                s  += __shfl_down(s, off);
                s2 += __shfl_down(s2, off);
            }
            if (ln == 0) { s_part[wv][o * 2] = s; s_part[wv][o * 2 + 1] = s2; }
        }
        __syncthreads();
        if (tid < 2 * COUT) {
            float t = s_part[0][tid] + s_part[1][tid] + s_part[2][tid] + s_part[3][tid];
            atomicAdd(&statacc[(size_t)p * COUT * 2 + tid], t);
        }
    }
}

// Level-0 fusion: deform-sample 4 neighbors from W0 + max with ego plane.
// Thread = (b, cg8, h, w), 8 channels. Occupancy ladder (counter-validated):
// CPT32/1024blk = 267µs @33% occ; CPT16/2048blk+swz ≈ 230µs (left top-5).
// CPT8/4096blk: grid cap 16 blocks/CU; live state ~50 VGPR stays in the
// <=64-VGPR band (32 waves/CU) WITHOUT a min-waves clause (round 1 proved
// forcing VGPR=32 spills: WRITE_SIZE 32->312MB). Latency-bound (VALUBusy 3%),
// so dur ~ 1/waves until HBM ~50%.
// XCD-chunked bijective swizzle (4096%8==0) for row reuse in per-XCD L2.
__global__ __launch_bounds__(256) void fuse0_kernel(
    const float* __restrict__ W0, const float* __restrict__ grid,
    float* __restrict__ out)
{
    constexpr int HW = 32768;
    constexpr int CPT = 8;
    int bid = blockIdx.x;
    int swz = (bid & 7) * 512 + (bid >> 3);
    int idx = swz * 256 + threadIdx.x;   // 4 * 8 * 32768
    int px = idx & 32767;
    int cg = (idx >> 15) & 7;
    int b  = idx >> 18;
    int w = px & 255, h = px >> 8;
    float bx = (w + 0.5f) * (2.f / 256.f) - 1.f;
    float by = (h + 0.5f) * (2.f / 128.f) - 1.f;
    Bilin bl[4];
    #pragma unroll
    for (int j = 0; j < 4; ++j) {
        const float2 g = *reinterpret_cast<const float2*>(
            grid + ((size_t)(b * 4 + j)) * 65536 + (size_t)px * 2);
        float ix = ((g.x + bx + 1.f) * 256.f - 1.f) * 0.5f;
        float iy = ((g.y + by + 1.f) * 128.f - 1.f) * 0.5f;
        bl[j] = make_bilin(ix, iy, 256, 128);
    }
    const float* ego = W0 + ((size_t)(b * 5) * 64 + cg * CPT) * HW + px;
    float* op = out + ((size_t)b * 64 + cg * CPT) * HW + px;
    #pragma unroll 2
    for (int c = 0; c < CPT; ++c) {
        float mx = ego[(size_t)c * HW];
        #pragma unroll
        for (int j = 0; j < 4; ++j) {
            const float* pl = W0 + ((size_t)(b * 5 + 1 + j) * 64 + cg * CPT + c) * HW;
            float s = pl[bl[j].i00] * bl[j].w00 + pl[bl[j].i01] * bl[j].w01 +
                      pl[bl[j].i10] * bl[j].w10 + pl[bl[j].i11] * bl[j].w11;
            mx = fmaxf(mx, s);
        }
        op[(size_t)c * HW] = mx;
    }
}

// Levels 1,2 fusion, composed: no materialized warp. Ego = inline affine
// sample; neighbor = outer bilinear (align_corners=False) over warped px,
// each warped px = inner affine bilinear of feat — 16 reads with
// premultiplied weights. Exact modulo fp association.
// CPT halved -> 1024 blocks (grid occupancy cap 25%->50%; latency-bound like
// fuse0); XCD-chunked bijective swizzle (1024%8==0). Kept from round 3
// (inferred −28µs vs round 2).
template<int C, int CPT, int SH, int HS, int WS>
__global__ __launch_bounds__(256) void fuse_comp(
    const float* __restrict__ feat, const float* __restrict__ tmat,
    const float* __restrict__ grid, float* __restrict__ out)
{
    constexpr int HW = HS * WS;
    constexpr int NCG = C / CPT;
    constexpr int NBLK = 4 * NCG * HW / 256;   // 1024 for both levels
    int bid = blockIdx.x;
    int swz = (bid & 7) * (NBLK / 8) + (bid >> 3);
    int idx = swz * 256 + threadIdx.x;
    if (idx >= 4 * NCG * HW) return;
    int px = idx % HW;
    int cg = (idx / HW) % NCG;
    int b  = idx / (HW * NCG);
    int w = px % WS, h = px / WS;

    float m[CPT];
    {   // ego
        const float* th = tmat + (size_t)(b * 25) * 6;
        float t0 = th[0], t1 = th[1], t2 = th[2], t3 = th[3], t4 = th[4], t5 = th[5];
        float thr[6] = {t0, t1, t2, t3, t4, t5};
        Bilin bi = affine_bilin(thr, w, h, WS, HS);
        const float* pb = feat + ((size_t)(b * 5) * C + cg * CPT) * HW;
        #pragma unroll 4
        for (int c = 0; c < CPT; ++c) {
            const float* pl = pb + (size_t)c * HW;
            m[c] = pl[bi.i00] * bi.w00 + pl[bi.i01] * bi.w01 +
                   pl[bi.i10] * bi.w10 + pl[bi.i11] * bi.w11;
        }
    }
    int h0 = h << SH, w0 = w << SH;
    float bx = (w0 + 0.5f) * (2.f / 256.f) - 1.f;
    float by = (h0 + 0.5f) * (2.f / 128.f) - 1.f;
    for (int j = 0; j < 4; ++j) {
        const float2 g = *reinterpret_cast<const float2*>(
            grid + ((size_t)(b * 4 + j)) * 65536 + (size_t)(h0 * 256 + w0) * 2);
        float ix = ((g.x + bx + 1.f) * WS - 1.f) * 0.5f;
        float iy = ((g.y + by + 1.f) * HS - 1.f) * 0.5f;
        // outer corners
        float x0f = floorf(ix), y0f = floorf(iy);
        float wx1 = ix - x0f, wy1 = iy - y0f;
        float wx0 = 1.f - wx1, wy0 = 1.f - wy1;
        int x0 = (int)x0f, y0 = (int)y0f, x1 = x0 + 1, y1 = y0 + 1;
        bool vx0 = (x0 >= 0 && x0 < WS), vx1 = (x1 >= 0 && x1 < WS);
        bool vy0 = (y0 >= 0 && y0 < HS), vy1 = (y1 >= 0 && y1 < HS);
        int cx0 = min(max(x0, 0), WS - 1), cx1 = min(max(x1, 0), WS - 1);
        int cy0 = min(max(y0, 0), HS - 1), cy1 = min(max(y1, 0), HS - 1);
        float ow[4] = { (vx0 && vy0) ? wx0 * wy0 : 0.f,
                        (vx1 && vy0) ? wx1 * wy0 : 0.f,
                        (vx0 && vy1) ? wx0 * wy1 : 0.f,
                        (vx1 && vy1) ? wx1 * wy1 : 0.f };
        int qx[4] = { cx0, cx1, cx0, cx1 };
        int qy[4] = { cy0, cy0, cy1, cy1 };
        const float* th = tmat + (size_t)(b * 25 + 1 + j) * 6;
        float thr[6] = { th[0], th[1], th[2], th[3], th[4], th[5] };
        Bilin in_[4];
        #pragma unroll
        for (int q = 0; q < 4; ++q) {
            in_[q] = affine_bilin(thr, qx[q], qy[q], WS, HS);
            in_[q].w00 *= ow[q]; in_[q].w01 *= ow[q];
            in_[q].w10 *= ow[q]; in_[q].w11 *= ow[q];
        }
        const float* pb = feat + ((size_t)(b * 5 + 1 + j) * C + cg * CPT) * HW;
        #pragma unroll 2
        for (int c = 0; c < CPT; ++c) {
            const float* pl = pb + (size_t)c * HW;
            float s = 0.f;
            #pragma unroll
            for (int q = 0; q < 4; ++q)
                s += pl[in_[q].i00] * in_[q].w00 + pl[in_[q].i01] * in_[q].w01 +
                     pl[in_[q].i10] * in_[q].w10 + pl[in_[q].i11] * in_[q].w11;
            m[c] = fmaxf(m[c], s);
        }
    }
    float* op = out + ((size_t)b * C + cg * CPT) * HW + px;
    #pragma unroll
    for (int c = 0; c < CPT; ++c) op[(size_t)c * HW] = m[c];
}

extern "C" void kernel_launch(void* const* d_in, const int* in_sizes, int n_in,
                              void* d_out, int out_size, void* d_ws, size_t ws_size,
                              hipStream_t stream)
{
    const float* feat0 = (const float*)d_in[0];
    const float* feat1 = (const float*)d_in[1];
    const float* feat2 = (const float*)d_in[2];
    const float* tmat  = (const float*)d_in[3];
    const float* w1 = (const float*)d_in[5];
    const float* b1 = (const float*)d_in[6];
    const float* w2 = (const float*)d_in[7];
    const float* b2 = (const float*)d_in[8];
    const float* w3 = (const float*)d_in[9];
    const float* b3 = (const float*)d_in[10];
    const float* w4 = (const float*)d_in[11];
    const float* b4 = (const float*)d_in[12];
    float* out = (float*)d_out;
    float* ws  = (float*)d_ws;

    // workspace layout (floats)
    const size_t nW0 = 41943040;  // 20*64*128*256
    const size_t nX1 = 16777216;  // 16*32*128*256
    const size_t nX2 = 8388608;   // 16*16*128*256
    const size_t nX3 = 4194304;   // 16*8*128*256
    const size_t nG  = 2097152;   // 16*2*128*256
    const size_t nS  = 2048;
    const size_t nWT = 36864 + 4608;
    const size_t needed = (nW0 + nX1 + nX2 + nX3 + nG + nS + nWT) * 4;
    if (ws_size < needed) return;

    float* W0  = ws;
    float* X1  = W0 + nW0;
    float* X2  = X1 + nX1;
    float* X3  = X2 + nX2;
    float* G   = X3 + nX3;
    float* S   = G  + nG;    // stats sums: X1@0(1024), X2@1024(512), X3@1536(256)
    float* WT1 = S  + nS;
    float* WT2 = WT1 + 36864;
    float* E   = X2;         // ego partials (4*32*32768) overlay X2 (dead until conv2)

    zero_stats<<<1, 256, 0, stream>>>(S);
    transpose_w<<<32, 256, 0, stream>>>(w1, w2, WT1, WT2);

    // level-0 affine warp (needed by conv1 and fuse0)
    warp_kernel<<<10240, 256, 0, stream>>>(feat0, tmat, W0, 64, 128, 256);

    // offset CNN: conv1 split into ego (once per batch) + neighbor (+init)
    conv3x3v3<64, 32, 1, false, false, false><<<256,  256, 0, stream>>>(W0, WT1, b1, nullptr, nullptr, E, nullptr);
    conv3x3v3<64, 32, 2, true,  false, true ><<<1024, 256, 0, stream>>>(W0, WT1 + 8 * 8 * 9 * 32, b1, nullptr, E, X1, S);
    finalize_stats<<<1, 512, 0, stream>>>(S, 512, 1.f / 32768.f);
    conv3x3v3<32, 16, 0, false, true,  true ><<<1024, 256, 0, stream>>>(X1, WT2, b2, S, nullptr, X2, S + 1024);
    finalize_stats<<<1, 256, 0, stream>>>(S + 1024, 256, 1.f / 32768.f);
    conv1x1_kernel<16, 8, true ><<<2048, 256, 0, stream>>>(X2, w3, b3, S + 1024, X3, S + 1536);
    finalize_stats<<<1, 128, 0, stream>>>(S + 1536, 128, 1.f / 32768.f);
    conv1x1_kernel<8, 2, false><<<2048, 256, 0, stream>>>(X3, w4, b4, S + 1536, G, nullptr);

    // fusion
    fuse0_kernel<<<4096, 256, 0, stream>>>(W0, G, out);
    fuse_comp<128, 16, 1, 64, 128><<<1024, 256, 0, stream>>>(feat1, tmat, G, out + 8388608);
    fuse_comp<256, 8, 2, 32,  64><<<1024, 256, 0, stream>>>(feat2, tmat, G, out + 12582912);
}

// Round 5
// 1290.986 us; speedup vs baseline: 1.0833x; 1.0331x over previous
//
#include <hip/hip_runtime.h>

// Problem constants: B=4, N=5, levels (64,128,256),(128,64,128),(256,32,64)

struct Bilin { int i00, i01, i10, i11; float w00, w01, w10, w11; };

__device__ __forceinline__ Bilin make_bilin(float ix, float iy, int W, int H) {
    float x0f = floorf(ix), y0f = floorf(iy);
    float wx1 = ix - x0f, wy1 = iy - y0f;
    float wx0 = 1.f - wx1, wy0 = 1.f - wy1;
    int x0 = (int)x0f, y0 = (int)y0f;
    int x1 = x0 + 1, y1 = y0 + 1;
    bool vx0 = (x0 >= 0 && x0 < W), vx1 = (x1 >= 0 && x1 < W);
    bool vy0 = (y0 >= 0 && y0 < H), vy1 = (y1 >= 0 && y1 < H);
    int cx0 = min(max(x0, 0), W - 1), cx1 = min(max(x1, 0), W - 1);
    int cy0 = min(max(y0, 0), H - 1), cy1 = min(max(y1, 0), H - 1);
    Bilin b;
    b.i00 = cy0 * W + cx0; b.i01 = cy0 * W + cx1;
    b.i10 = cy1 * W + cx0; b.i11 = cy1 * W + cx1;
    b.w00 = (vx0 && vy0) ? wx0 * wy0 : 0.f;
    b.w01 = (vx1 && vy0) ? wx1 * wy0 : 0.f;
    b.w10 = (vx0 && vy1) ? wx0 * wy1 : 0.f;
    b.w11 = (vx1 && vy1) ? wx1 * wy1 : 0.f;
    return b;
}

// Inner sample: warped value at integer px (xq,yq) = affine sample of feat
// (align_corners=True on both the base grid and the sampling).
__device__ __forceinline__ Bilin affine_bilin(const float* th, int xq, int yq, int W, int H) {
    float gx = -1.f + 2.f * xq / (float)(W - 1);
    float gy = -1.f + 2.f * yq / (float)(H - 1);
    float tx = th[0] * gx + th[1] * gy + th[2];
    float ty = th[3] * gx + th[4] * gy + th[5];
    float ix = (tx + 1.f) * 0.5f * (W - 1);
    float iy = (ty + 1.f) * 0.5f * (H - 1);
    return make_bilin(ix, iy, W, H);
}

// Affine warp (align_corners=True), level 0 only. Thread = (img, cg16, h, w).
__global__ __launch_bounds__(256) void warp_kernel(
    const float* __restrict__ src, const float* __restrict__ tmat,
    float* __restrict__ dst, int C, int H, int W)
{
    int idx = blockIdx.x * 256 + threadIdx.x;
    int CGn = C >> 4;
    int HW = H * W;
    int total = 20 * CGn * HW;
    if (idx >= total) return;
    int w   = idx % W;
    int h   = (idx / W) % H;
    int cg  = (idx / HW) % CGn;
    int img = idx / (HW * CGn);
    int b = img / 5, n = img % 5;
    const float* th = tmat + (b * 25 + n) * 6;
    float gx = -1.f + 2.f * w / (float)(W - 1);
    float gy = -1.f + 2.f * h / (float)(H - 1);
    float tx = th[0] * gx + th[1] * gy + th[2];
    float ty = th[3] * gx + th[4] * gy + th[5];
    float ix = (tx + 1.f) * 0.5f * (W - 1);
    float iy = (ty + 1.f) * 0.5f * (H - 1);
    Bilin bl = make_bilin(ix, iy, W, H);
    const float* im = src + ((size_t)img * C + cg * 16) * HW;
    float* op = dst + ((size_t)img * C + cg * 16) * HW + h * W + w;
    #pragma unroll 4
    for (int c = 0; c < 16; ++c) {
        const float* pl = im + c * HW;
        op[c * HW] = pl[bl.i00] * bl.w00 + pl[bl.i01] * bl.w01 +
                     pl[bl.i10] * bl.w10 + pl[bl.i11] * bl.w11;
    }
}

// Zero the stats accumulator region (1792 floats).
__global__ void zero_stats(float* s) {
    for (int i = threadIdx.x; i < 1792; i += 256) s[i] = 0.f;
}

// sums -> (mean, rsqrt(var+eps)) in place. n pairs.
__global__ void finalize_stats(float* s, int n, float inv_hw) {
    int i = threadIdx.x;
    if (i < n) {
        float m = s[2 * i] * inv_hw;
        float v = s[2 * i + 1] * inv_hw - m * m;
        s[2 * i]     = m;
        s[2 * i + 1] = rsqrtf(v + 1e-5f);
    }
}

// Pre-transpose conv weights to [cin][pos][COUT].
__global__ void transpose_w(const float* __restrict__ w1, const float* __restrict__ w2,
                            float* __restrict__ wt1, float* __restrict__ wt2) {
    int t = blockIdx.x * 256 + threadIdx.x;
    for (int i = t; i < 128 * 9 * 32; i += 32 * 256) {
        int o = i % 32, pos = (i / 32) % 9, cin = i / 288;
        wt1[i] = w1[o * 1152 + cin * 9 + pos];
    }
    for (int i = t; i < 32 * 9 * 16; i += 32 * 256) {
        int o = i % 16, pos = (i / 16) % 9, cin = i / 144;
        wt2[i] = w2[o * 288 + cin * 9 + pos];
    }
}

// Direct 3x3 conv v5, pad=1, H=128 W=256.
// Tile 8x64; thread = 8 px x OCP couts. Weights via wave-uniform (scalar)
// loads from pre-transposed [cin][pos][COUT]; input staged through LDS with
// a register-prefetch pipeline. v5: SPLIT template — split a block's couts
// across SPLIT blocks (OCP = COUT/(4*SPLIT)). Rationale (counter arithmetic,
// round 4): conv1 ran at VALUBusy 59% / occupancy 25% (VGPR=80: acc[8][8]=64
// regs pins the 64<v<=128 band -> 16 waves/CU cap; grid 4 blocks/CU). SPLIT=2
// halves acc to 32 -> VGPR <=64 band (32 waves/CU); LDS 22016B admits 7
// blocks/CU; grid doubles. Cost: input tile staged twice; cout-half mapped to
// the HIGH block-index bit (UNITS%8==0) so siblings share an XCD's L2.
// Scheduling fixes at 2 blocks/CU were tried and failed (r2 lane-map: conflict
// counter is structural; r3 LDS-weight pipeline: regressed, no TLP to hide
// added ds latency) — occupancy is the remaining counter-backed lever.
// SRC: 0 plain NCHW; 1 ego (img p<4 -> plane p*5+0); 2 neigh (p<16 -> b*5+1+j).
// INIT: acc += init (ego partials). NORM: IN+leaky on input. STATS: fused
// per-(img,cout) sum/sumsq via wave-reduce + atomicAdd into statacc.
template<int CIN, int COUT, int SPLIT, int SRC, bool INIT, bool NORM, bool STATS>
__global__ __launch_bounds__(256, 2) void conv3x3v5(
    const float* __restrict__ src, const float* __restrict__ wt,
    const float* __restrict__ bias, const float* __restrict__ stats,
    const float* __restrict__ init, float* __restrict__ dst,
    float* __restrict__ statacc)
{
    constexpr int H = 128, W = 256, HW = H * W;
    constexpr int CHUNK = 8, NCH = CIN / CHUNK;
    constexpr int COUTB = COUT / SPLIT;     // couts this block computes
    constexpr int OCP = COUTB / 4;
    constexpr int PW = 68;
    constexpr int UNITS = ((SRC == 1) ? 4 : 16) * 64;  // (p,tile) units
    __shared__ __align__(16) float s_in[CHUNK][10][PW];

    int tid = threadIdx.x, bi = blockIdx.x;
    int ch = bi / UNITS;                    // cout-half (high bits: sibling
    int u  = bi % UNITS;                    // blocks UNITS apart -> same XCD)
    int p = u >> 6, rem = u & 63;
    int h_base = (rem >> 2) * 8;
    int w_base = (rem & 3) * 64;
    int cg = tid >> 6, sg = tid & 63;
    int r = sg & 7, cw = (sg >> 3) * 8;
    int cg_u = __builtin_amdgcn_readfirstlane(cg);
    int ocb = ch * COUTB;                   // global cout base for this block

    const float* base;
    if (SRC == 1)      base = src + (size_t)(p * 5) * 64 * HW;
    else if (SRC == 2) { int bb = p >> 2, jm = p & 3; base = src + (size_t)((bb * 5 + 1 + jm) * 64) * HW; }
    else               base = src + (size_t)p * CIN * HW;

    // staging positions: e = tid + k*256 over the 10x66 halo tile (660 slots)
    int gofs[3], lofs[3];
    unsigned pvm = 0, ivm = 0;
    #pragma unroll
    for (int k = 0; k < 3; ++k) {
        int e = tid + k * 256;
        bool pv = (e < 660);
        int row = e / 66, col = e % 66;
        int gy = h_base + row - 1, gx = w_base + col - 1;
        bool iv = pv && gy >= 0 && gy < H && gx >= 0 && gx < W;
        gofs[k] = iv ? (gy * W + gx) : 0;
        lofs[k] = pv ? (row * PW + col) : 0;
        pvm |= (pv ? 1u : 0u) << k;
        ivm |= (iv ? 1u : 0u) << k;
    }
    float* lds = &s_in[0][0][0];

    float acc[OCP][8];
    #pragma unroll
    for (int o = 0; o < OCP; ++o)
        #pragma unroll
        for (int i = 0; i < 8; ++i) acc[o][i] = 0.f;

    float pf[3][CHUNK];
    // prefetch chunk 0
    #pragma unroll
    for (int k = 0; k < 3; ++k)
        if (pvm >> k & 1)
            #pragma unroll
            for (int c = 0; c < CHUNK; ++c)
                pf[k][c] = base[(size_t)c * HW + gofs[k]];

    for (int ci = 0; ci < NCH; ++ci) {
        if (ci) __syncthreads();
        // store prefetched chunk to LDS (apply IN+leaky here if NORM)
        float mrs[NORM ? 2 * CHUNK : 1];
        if (NORM) {
            const float4* sp = (const float4*)(stats + (size_t)(p * CIN + ci * CHUNK) * 2);
            #pragma unroll
            for (int q = 0; q < CHUNK / 2; ++q) {
                float4 v = sp[q];
                mrs[q * 4] = v.x; mrs[q * 4 + 1] = v.y; mrs[q * 4 + 2] = v.z; mrs[q * 4 + 3] = v.w;
            }
        }
        #pragma unroll
        for (int k = 0; k < 3; ++k) {
            if (pvm >> k & 1) {
                #pragma unroll
                for (int c = 0; c < CHUNK; ++c) {
                    float v = (ivm >> k & 1) ? pf[k][c] : 0.f;
                    if (NORM && (ivm >> k & 1)) {
                        v = (v - mrs[2 * c]) * mrs[2 * c + 1];
                        v = v >= 0.f ? v : 0.01f * v;
                    }
                    lds[c * (10 * PW) + lofs[k]] = v;
                }
            }
        }
        __syncthreads();
        // prefetch next chunk
        if (ci + 1 < NCH) {
            const float* nb = base + (size_t)(ci + 1) * CHUNK * HW;
            #pragma unroll
            for (int k = 0; k < 3; ++k)
                if (pvm >> k & 1)
                    #pragma unroll
                    for (int c = 0; c < CHUNK; ++c)
                        pf[k][c] = nb[(size_t)c * HW + gofs[k]];
        }
        // compute chunk ci
        #pragma unroll 1
        for (int c = 0; c < CHUNK; ++c) {
            float in[3][10];
            #pragma unroll
            for (int dy = 0; dy < 3; ++dy) {
                const float* rp = &s_in[c][r + dy][cw];
                float4 a = *reinterpret_cast<const float4*>(rp);
                float4 b = *reinterpret_cast<const float4*>(rp + 4);
                float2 e = *reinterpret_cast<const float2*>(rp + 8);
                in[dy][0] = a.x; in[dy][1] = a.y; in[dy][2] = a.z; in[dy][3] = a.w;
                in[dy][4] = b.x; in[dy][5] = b.y; in[dy][6] = b.z; in[dy][7] = b.w;
                in[dy][8] = e.x; in[dy][9] = e.y;
            }
            const float* wp = wt + (size_t)((ci * CHUNK + c) * 9) * COUT + ocb + cg_u * OCP;
            #pragma unroll
            for (int pos = 0; pos < 9; ++pos) {
                const int dy = pos / 3, dx = pos % 3;
                float wv[OCP];
                #pragma unroll
                for (int oq = 0; oq < OCP; oq += 4) {
                    float4 wq = *reinterpret_cast<const float4*>(wp + pos * COUT + oq);
                    wv[oq] = wq.x; wv[oq + 1] = wq.y; wv[oq + 2] = wq.z; wv[oq + 3] = wq.w;
                }
                #pragma unroll
                for (int o = 0; o < OCP; ++o)
                    #pragma unroll
                    for (int px = 0; px < 8; ++px)
                        acc[o][px] = fmaf(in[dy][dx + px], wv[o], acc[o][px]);
            }
        }
    }
    // epilogue
    int hh = h_base + r, ww = w_base + cw;
    #pragma unroll
    for (int o = 0; o < OCP; ++o) {
        int oc = ocb + cg * OCP + o;
        float bv = (SRC == 1) ? 0.f : bias[oc];
        float add[8];
        #pragma unroll
        for (int i = 0; i < 8; ++i) add[i] = bv;
        if (INIT) {
            int bb = (SRC == 2) ? (p >> 2) : p;
            const float* ip = init + ((size_t)bb * COUT + oc) * HW + hh * W + ww;
            float4 e0 = *reinterpret_cast<const float4*>(ip);
            float4 e1 = *reinterpret_cast<const float4*>(ip + 4);
            add[0] += e0.x; add[1] += e0.y; add[2] += e0.z; add[3] += e0.w;
            add[4] += e1.x; add[5] += e1.y; add[6] += e1.z; add[7] += e1.w;
        }
        float vals[8];
        #pragma unroll
        for (int i = 0; i < 8; ++i) vals[i] = acc[o][i] + add[i];
        float* op = dst + (((size_t)p * COUT + oc) * H + hh) * W + ww;
        *reinterpret_cast<float4*>(op)     = make_float4(vals[0], vals[1], vals[2], vals[3]);
        *reinterpret_cast<float4*>(op + 4) = make_float4(vals[4], vals[5], vals[6], vals[7]);
        if (STATS) {
            float s = 0.f, s2 = 0.f;
            #pragma unroll
            for (int i = 0; i < 8; ++i) { s += vals[i]; s2 += vals[i] * vals[i]; }
            #pragma unroll
            for (int off = 32; off > 0; off >>= 1) {
                s  += __shfl_down(s, off);
                s2 += __shfl_down(s2, off);
            }
            if (sg == 0) {
                atomicAdd(&statacc[(size_t)(p * COUT + oc) * 2],     s);
                atomicAdd(&statacc[(size_t)(p * COUT + oc) * 2 + 1], s2);
            }
        }
    }
}

// 1x1 conv with fused IN+leaky on input; optional fused stats on output.
template<int CIN, int COUT, bool STATS>
__global__ __launch_bounds__(256) void conv1x1_kernel(
    const float* __restrict__ src, const float* __restrict__ wgt,
    const float* __restrict__ bias, const float* __restrict__ stats,
    float* __restrict__ dst, float* __restrict__ statacc)
{
    constexpr int HW = 128 * 256;
    __shared__ float s_w[COUT * CIN];
    __shared__ float s_b[COUT];
    __shared__ float s_part[4][2 * COUT];
    int tid = threadIdx.x;
    for (int t = tid; t < COUT * CIN; t += 256) s_w[t] = wgt[t];
    if (tid < COUT) s_b[tid] = bias[tid];
    __syncthreads();
    int p  = blockIdx.x >> 7;
    int px = ((blockIdx.x & 127) << 8) + tid;
    float in[CIN];
    #pragma unroll
    for (int c = 0; c < CIN; ++c) {
        float v  = src[((size_t)p * CIN + c) * HW + px];
        float m  = stats[(p * CIN + c) * 2];
        float rs = stats[(p * CIN + c) * 2 + 1];
        v = (v - m) * rs;
        in[c] = v >= 0.f ? v : 0.01f * v;
    }
    float val[COUT];
    #pragma unroll
    for (int o = 0; o < COUT; ++o) {
        float s = s_b[o];
        #pragma unroll
        for (int c = 0; c < CIN; ++c) s = fmaf(in[c], s_w[o * CIN + c], s);
        val[o] = s;
        dst[((size_t)p * COUT + o) * HW + px] = s;
    }
    if (STATS) {
        int wv = tid >> 6, ln = tid & 63;
        #pragma unroll
        for (int o = 0; o < COUT; ++o) {
            float s = val[o], s2 = val[o] * val[o];
            #pragma unroll
            for (int off = 32; off > 0; off >>= 1) {
                s  += __shfl_down(s, off);
                s2 += __shfl_down(s2, off);
            }
            if (ln == 0) { s_part[wv][o * 2] = s; s_part[wv][o * 2 + 1] = s2; }
        }
        __syncthreads();
        if (tid < 2 * COUT) {
            float t = s_part[0][tid] + s_part[1][tid] + s_part[2][tid] + s_part[3][tid];
            atomicAdd(&statacc[(size_t)p * COUT * 2 + tid], t);
        }
    }
}

// Level-0 fusion: deform-sample 4 neighbors from W0 + max with ego plane.
// Thread = (b, cg8, h, w), 8 channels; 4096 blocks (counter-validated
// occupancy ladder: 267µs@CPT32 -> ~230@CPT16 -> left top-5 @CPT8). No
// min-waves clause (forcing VGPR=32 spills, round 1).
// XCD-chunked bijective swizzle (4096%8==0) for row reuse in per-XCD L2.
__global__ __launch_bounds__(256) void fuse0_kernel(
    const float* __restrict__ W0, const float* __restrict__ grid,
    float* __restrict__ out)
{
    constexpr int HW = 32768;
    constexpr int CPT = 8;
    int bid = blockIdx.x;
    int swz = (bid & 7) * 512 + (bid >> 3);
    int idx = swz * 256 + threadIdx.x;   // 4 * 8 * 32768
    int px = idx & 32767;
    int cg = (idx >> 15) & 7;
    int b  = idx >> 18;
    int w = px & 255, h = px >> 8;
    float bx = (w + 0.5f) * (2.f / 256.f) - 1.f;
    float by = (h + 0.5f) * (2.f / 128.f) - 1.f;
    Bilin bl[4];
    #pragma unroll
    for (int j = 0; j < 4; ++j) {
        const float2 g = *reinterpret_cast<const float2*>(
            grid + ((size_t)(b * 4 + j)) * 65536 + (size_t)px * 2);
        float ix = ((g.x + bx + 1.f) * 256.f - 1.f) * 0.5f;
        float iy = ((g.y + by + 1.f) * 128.f - 1.f) * 0.5f;
        bl[j] = make_bilin(ix, iy, 256, 128);
    }
    const float* ego = W0 + ((size_t)(b * 5) * 64 + cg * CPT) * HW + px;
    float* op = out + ((size_t)b * 64 + cg * CPT) * HW + px;
    #pragma unroll 2
    for (int c = 0; c < CPT; ++c) {
        float mx = ego[(size_t)c * HW];
        #pragma unroll
        for (int j = 0; j < 4; ++j) {
            const float* pl = W0 + ((size_t)(b * 5 + 1 + j) * 64 + cg * CPT + c) * HW;
            float s = pl[bl[j].i00] * bl[j].w00 + pl[bl[j].i01] * bl[j].w01 +
                      pl[bl[j].i10] * bl[j].w10 + pl[bl[j].i11] * bl[j].w11;
            mx = fmaxf(mx, s);
        }
        op[(size_t)c * HW] = mx;
    }
}

// Levels 1,2 fusion, composed: no materialized warp. Ego = inline affine
// sample; neighbor = outer bilinear (align_corners=False) over warped px,
// each warped px = inner affine bilinear of feat — 16 reads with
// premultiplied weights. Exact modulo fp association.
// 1024 blocks (CPT halved r3); XCD-chunked bijective swizzle (1024%8==0).
template<int C, int CPT, int SH, int HS, int WS>
__global__ __launch_bounds__(256) void fuse_comp(
    const float* __restrict__ feat, const float* __restrict__ tmat,
    const float* __restrict__ grid, float* __restrict__ out)
{
    constexpr int HW = HS * WS;
    constexpr int NCG = C / CPT;
    constexpr int NBLK = 4 * NCG * HW / 256;   // 1024 for both levels
    int bid = blockIdx.x;
    int swz = (bid & 7) * (NBLK / 8) + (bid >> 3);
    int idx = swz * 256 + threadIdx.x;
    if (idx >= 4 * NCG * HW) return;
    int px = idx % HW;
    int cg = (idx / HW) % NCG;
    int b  = idx / (HW * NCG);
    int w = px % WS, h = px / WS;

    float m[CPT];
    {   // ego
        const float* th = tmat + (size_t)(b * 25) * 6;
        float t0 = th[0], t1 = th[1], t2 = th[2], t3 = th[3], t4 = th[4], t5 = th[5];
        float thr[6] = {t0, t1, t2, t3, t4, t5};
        Bilin bi = affine_bilin(thr, w, h, WS, HS);
        const float* pb = feat + ((size_t)(b * 5) * C + cg * CPT) * HW;
        #pragma unroll 4
        for (int c = 0; c < CPT; ++c) {
            const float* pl = pb + (size_t)c * HW;
            m[c] = pl[bi.i00] * bi.w00 + pl[bi.i01] * bi.w01 +
                   pl[bi.i10] * bi.w10 + pl[bi.i11] * bi.w11;
        }
    }
    int h0 = h << SH, w0 = w << SH;
    float bx = (w0 + 0.5f) * (2.f / 256.f) - 1.f;
    float by = (h0 + 0.5f) * (2.f / 128.f) - 1.f;
    for (int j = 0; j < 4; ++j) {
        const float2 g = *reinterpret_cast<const float2*>(
            grid + ((size_t)(b * 4 + j)) * 65536 + (size_t)(h0 * 256 + w0) * 2);
        float ix = ((g.x + bx + 1.f) * WS - 1.f) * 0.5f;
        float iy = ((g.y + by + 1.f) * HS - 1.f) * 0.5f;
        // outer corners
        float x0f = floorf(ix), y0f = floorf(iy);
        float wx1 = ix - x0f, wy1 = iy - y0f;
        float wx0 = 1.f - wx1, wy0 = 1.f - wy1;
        int x0 = (int)x0f, y0 = (int)y0f, x1 = x0 + 1, y1 = y0 + 1;
        bool vx0 = (x0 >= 0 && x0 < WS), vx1 = (x1 >= 0 && x1 < WS);
        bool vy0 = (y0 >= 0 && y0 < HS), vy1 = (y1 >= 0 && y1 < HS);
        int cx0 = min(max(x0, 0), WS - 1), cx1 = min(max(x1, 0), WS - 1);
        int cy0 = min(max(y0, 0), HS - 1), cy1 = min(max(y1, 0), HS - 1);
        float ow[4] = { (vx0 && vy0) ? wx0 * wy0 : 0.f,
                        (vx1 && vy0) ? wx1 * wy0 : 0.f,
                        (vx0 && vy1) ? wx0 * wy1 : 0.f,
                        (vx1 && vy1) ? wx1 * wy1 : 0.f };
        int qx[4] = { cx0, cx1, cx0, cx1 };
        int qy[4] = { cy0, cy0, cy1, cy1 };
        const float* th = tmat + (size_t)(b * 25 + 1 + j) * 6;
        float thr[6] = { th[0], th[1], th[2], th[3], th[4], th[5] };
        Bilin in_[4];
        #pragma unroll
        for (int q = 0; q < 4; ++q) {
            in_[q] = affine_bilin(thr, qx[q], qy[q], WS, HS);
            in_[q].w00 *= ow[q]; in_[q].w01 *= ow[q];
            in_[q].w10 *= ow[q]; in_[q].w11 *= ow[q];
        }
        const float* pb = feat + ((size_t)(b * 5 + 1 + j) * C + cg * CPT) * HW;
        #pragma unroll 2
        for (int c = 0; c < CPT; ++c) {
            const float* pl = pb + (size_t)c * HW;
            float s = 0.f;
            #pragma unroll
            for (int q = 0; q < 4; ++q)
                s += pl[in_[q].i00] * in_[q].w00 + pl[in_[q].i01] * in_[q].w01 +
                     pl[in_[q].i10] * in_[q].w10 + pl[in_[q].i11] * in_[q].w11;
            m[c] = fmaxf(m[c], s);
        }
    }
    float* op = out + ((size_t)b * C + cg * CPT) * HW + px;
    #pragma unroll
    for (int c = 0; c < CPT; ++c) op[(size_t)c * HW] = m[c];
}

extern "C" void kernel_launch(void* const* d_in, const int* in_sizes, int n_in,
                              void* d_out, int out_size, void* d_ws, size_t ws_size,
                              hipStream_t stream)
{
    const float* feat0 = (const float*)d_in[0];
    const float* feat1 = (const float*)d_in[1];
    const float* feat2 = (const float*)d_in[2];
    const float* tmat  = (const float*)d_in[3];
    const float* w1 = (const float*)d_in[5];
    const float* b1 = (const float*)d_in[6];
    const float* w2 = (const float*)d_in[7];
    const float* b2 = (const float*)d_in[8];
    const float* w3 = (const float*)d_in[9];
    const float* b3 = (const float*)d_in[10];
    const float* w4 = (const float*)d_in[11];
    const float* b4 = (const float*)d_in[12];
    float* out = (float*)d_out;
    float* ws  = (float*)d_ws;

    // workspace layout (floats)
    const size_t nW0 = 41943040;  // 20*64*128*256
    const size_t nX1 = 16777216;  // 16*32*128*256
    const size_t nX2 = 8388608;   // 16*16*128*256
    const size_t nX3 = 4194304;   // 16*8*128*256
    const size_t nG  = 2097152;   // 16*2*128*256
    const size_t nS  = 2048;
    const size_t nWT = 36864 + 4608;
    const size_t needed = (nW0 + nX1 + nX2 + nX3 + nG + nS + nWT) * 4;
    if (ws_size < needed) return;

    float* W0  = ws;
    float* X1  = W0 + nW0;
    float* X2  = X1 + nX1;
    float* X3  = X2 + nX2;
    float* G   = X3 + nX3;
    float* S   = G  + nG;    // stats sums: X1@0(1024), X2@1024(512), X3@1536(256)
    float* WT1 = S  + nS;
    float* WT2 = WT1 + 36864;
    float* E   = X2;         // ego partials (4*32*32768) overlay X2 (dead until conv2)

    zero_stats<<<1, 256, 0, stream>>>(S);
    transpose_w<<<32, 256, 0, stream>>>(w1, w2, WT1, WT2);

    // level-0 affine warp (needed by conv1 and fuse0)
    warp_kernel<<<10240, 256, 0, stream>>>(feat0, tmat, W0, 64, 128, 256);

    // offset CNN: conv1 split into ego (once per batch) + neighbor (+init);
    // SPLIT=2 on both conv1 stages (occupancy: acc 64->32 regs).
    conv3x3v5<64, 32, 2, 1, false, false, false><<<512,  256, 0, stream>>>(W0, WT1, b1, nullptr, nullptr, E, nullptr);
    conv3x3v5<64, 32, 2, 2, true,  false, true ><<<2048, 256, 0, stream>>>(W0, WT1 + 8 * 8 * 9 * 32, b1, nullptr, E, X1, S);
    finalize_stats<<<1, 512, 0, stream>>>(S, 512, 1.f / 32768.f);
    conv3x3v5<32, 16, 1, 0, false, true,  true ><<<1024, 256, 0, stream>>>(X1, WT2, b2, S, nullptr, X2, S + 1024);
    finalize_stats<<<1, 256, 0, stream>>>(S + 1024, 256, 1.f / 32768.f);
    conv1x1_kernel<16, 8, true ><<<2048, 256, 0, stream>>>(X2, w3, b3, S + 1024, X3, S + 1536);
    finalize_stats<<<1, 128, 0, stream>>>(S + 1536, 128, 1.f / 32768.f);
    conv1x1_kernel<8, 2, false><<<2048, 256, 0, stream>>>(X3, w4, b4, S + 1536, G, nullptr);

    // fusion
    fuse0_kernel<<<4096, 256, 0, stream>>>(W0, G, out);
    fuse_comp<128, 16, 1, 64, 128><<<1024, 256, 0, stream>>>(feat1, tmat, G, out + 8388608);
    fuse_comp<256, 8, 2, 32,  64><<<1024, 256, 0, stream>>>(feat2, tmat, G, out + 12582912);
}